// Round 4
// baseline (2196.297 us; speedup 1.0000x reference)
//
#include <hip/hip_runtime.h>
#include <cstddef>
#include <cstdint>

typedef _Float16 f16x8 __attribute__((ext_vector_type(8)));
typedef _Float16 f16x4 __attribute__((ext_vector_type(4)));
typedef float    f32x16 __attribute__((ext_vector_type(16)));

// ---------------------------------------------------------------------------
// Weight transform: OIHW fp32 -> Bt[kstep][g][lane][8j] fp16 (frag-native for
// mfma_f32_32x32x16_f16 B operand: n = lane&31, k = (lane>>5)*8 + j).
// kstep = (chunk*K + ky)*R + run; flat = run*16 + k; x_off = flat/20,
// ic = chunk*20 + flat%20. Zero for oc>=OC, ic>=IC, x_off>=K.
// ---------------------------------------------------------------------------
__global__ __launch_bounds__(256) void wtrans_kernel(
    const float* __restrict__ w, _Float16* __restrict__ Bt,
    int IC, int OC, int G, int K, int R, int ksteps)
{
    int gid = blockIdx.x * 256 + threadIdx.x;
    if (gid >= ksteps * G * 64) return;
    int ks   = gid / (G * 64);
    int rr   = gid - ks * G * 64;
    int g    = rr >> 6;
    int lane = rr & 63;
    int run = ks % R;
    int t2  = ks / R;
    int ky  = t2 % K;
    int chunk = t2 / K;
    int oc = g * 32 + (lane & 31);
    int kh = lane >> 5;
    _Float16 tmp[8];
    #pragma unroll
    for (int j = 0; j < 8; ++j) {
        int flat = run * 16 + kh * 8 + j;
        int xo  = flat / 20;
        int icl = flat - xo * 20;
        int ic  = chunk * 20 + icl;
        float v = 0.0f;
        if (oc < OC && ic < IC && xo < K)
            v = w[(((size_t)oc * IC + ic) * K + ky) * K + xo];
        tmp[j] = (_Float16)v;
    }
    *(uint4*)(Bt + (size_t)gid * 8) = *(uint4*)tmp;
}

// ---------------------------------------------------------------------------
// Input pre-convert: NCHW fp32 (200ch) -> chunked fp16 [img][10][268][268*20].
// ---------------------------------------------------------------------------
__global__ __launch_bounds__(256) void convin_kernel(
    const float* __restrict__ src, _Float16* __restrict__ dst, int IC)
{
    constexpr int W = 268;
    constexpr int PADS = 272;
    __shared__ float s[20 * PADS];
    int y = blockIdx.x, chunk = blockIdx.y, img = blockIdx.z;
    int tid = threadIdx.x;
    for (int e = tid; e < 20 * W; e += 256) {
        int icl = e / W;
        int x = e - icl * W;
        int ic = chunk * 20 + icl;
        float v = 0.0f;
        if (ic < IC)
            v = src[(((size_t)img * IC + ic) * W + y) * W + x];
        s[icl * PADS + x] = v;
    }
    __syncthreads();
    _Float16* outRow = dst + ((size_t)(img * 10 + chunk) * W + y) * (W * 20);
    for (int u = tid; u < W * 20 / 8; u += 256) {
        _Float16 t[8];
        #pragma unroll
        for (int q = 0; q < 8; ++q) {
            int e = u * 8 + q;
            int px = e / 20;
            int c  = e - px * 20;
            t[q] = (_Float16)s[c * PADS + px];
        }
        *(uint4*)(outRow + (size_t)u * 8) = *(uint4*)t;
    }
}

// ---------------------------------------------------------------------------
// Implicit-GEMM conv, MFMA 32x32x16 fp16.
// R4: LDS-BW-driven re-tile. The invariant bottleneck R0-R3 was A-fragment
// LDS reads: 16 B/lane per read feeding nt MFMAs = 1024/nt B per MFMA; at
// nt=2 that is 254 B/cyc/CU demand at MFMA saturation vs ~112 B/cyc LDS
// ceiling -> MfmaUtil pinned at ~44% at ANY occupancy (R3 proved).
// Changes:
//  (1) nt = NT = all oc32 groups (4 for OC=100 layers, 2 for OC=50): one
//      A-read feeds NT MFMAs -> 256 B/MFMA.
//  (2) run-outer / ky-inner loop order with a 2-fragment rolling register
//      window: rows {wm*2+ky, wm*2+ky+1} overlap between consecutive ky, so
//      each (row,run) fragment is ds_read ONCE ((K+1) reads per run-column
//      instead of 2K). Static indices via fully-unrolled ky (rule #20).
// Net LDS demand ~71 B/cyc/CU < 112 ceiling. B stays global (L1/L2).
// Block: 8 y-rows x 32 px x NT*32 oc; 4 waves, wave wm owns y-pair, acc[2][NT].
// NT=4: ~198 regs -> 2 blocks/CU; NT=2: ~120 -> 3 blocks/CU.
// m-tile = 1 y-row x 32 x; A lane: m=lane&31 (x), k=(lane>>5)*8+j.
// C/D: col(n)=lane&31, row(x)=(reg&3)+8*(reg>>2)+4*(lane>>5).
// ---------------------------------------------------------------------------
template<int K, int NT, bool RELU>
__global__ __launch_bounds__(256, (NT == 4) ? 2 : 3) void conv_mfma(
    const _Float16* __restrict__ in, const _Float16* __restrict__ Bt,
    const float* __restrict__ bias, _Float16* __restrict__ out,
    int Hin, int Win, int OC, int Ho, int Wo,
    int nchunks, int xb, int tilesPerImg,
    long inStride, long outStride)
{
    constexpr int CB = 20;
    constexpr int R  = (K * CB + 15) / 16;
    constexpr int BM = 8;
    constexpr int PH = BM + K - 1;
    constexpr int MAXF = 31 * CB + R * 16;
    constexpr int PW = (((MAXF + CB - 1) / CB) + 1) & ~1;
    constexpr int ROWF = PW * CB;          // f16 per LDS row
    constexpr int UROW = ROWF / 8;         // 16B units per row
    constexpr int TOT  = PH * UROW;        // 16B units per buffer
    constexpr int KSF  = NT * 512;         // f16 per kstep in Bt (G == NT)

    __shared__ __align__(16) _Float16 s[PH * ROWF];

    const int tid  = threadIdx.x;
    const int lane = tid & 63;
    const int wm   = tid >> 6;             // wave owns rows {wm*2, wm*2+1}
    const int mcol = lane & 31;
    const int kh   = lane >> 5;
    const int alane = mcol * CB + kh * 8;

    int t = blockIdx.x;
    int img = t / tilesPerImg;
    int rem = t - img * tilesPerImg;
    int byi = rem / xb;
    int bxi = rem - byi * xb;
    int y0 = byi * BM; if (y0 > Ho - BM) y0 = Ho - BM;
    int x0 = bxi * 32; if (x0 > Wo - 32) x0 = Wo - 32;

    const _Float16* inI = in + (size_t)img * inStride;

    f32x16 acc[2][NT];
    #pragma unroll
    for (int m = 0; m < 2; ++m)
        #pragma unroll
        for (int n = 0; n < NT; ++n)
            acc[m][n] = (f32x16)(0.0f);

    const int rowE = Win * CB;
    const int mxo  = rowE - 8;
    const size_t chStride = (size_t)Hin * rowE;

    #pragma unroll 1
    for (int chunk = 0; chunk < nchunks; ++chunk) {
        // ---- stage A patch (contiguous 16B units per row, clamped) ----
        const _Float16* inC = inI + chunk * chStride + (size_t)y0 * rowE;
        #pragma unroll 1
        for (int e = tid; e < TOT; e += 256) {
            int py = e / UROW;
            int uu = e - py * UROW;
            int off = x0 * CB + uu * 8;
            if (off > mxo) off = mxo;     // clamped slots only feed zero-B taps
            uint4 val = *(const uint4*)(inC + (size_t)py * rowE + off);
            *(uint4*)&s[(size_t)e * 8] = val;
        }
        __syncthreads();

        const _Float16* BtC = Bt + (size_t)(chunk * K) * R * KSF;
        #pragma unroll 1
        for (int run = 0; run < R; ++run) {
            const int abase = alane + run * 16;
            // rolling 2-fragment window over rows wm*2 .. wm*2+K
            f16x8 frag[2];
            {
                const _Float16* ap = &s[(wm * 2) * ROWF + abase];
                f16x4 lo = *(const f16x4*)ap;
                f16x4 hi = *(const f16x4*)(ap + 4);
                frag[0] = __builtin_shufflevector(lo, hi, 0, 1, 2, 3, 4, 5, 6, 7);
            }
            #pragma unroll
            for (int ky = 0; ky < K; ++ky) {
                {
                    const _Float16* ap = &s[(wm * 2 + ky + 1) * ROWF + abase];
                    f16x4 lo = *(const f16x4*)ap;
                    f16x4 hi = *(const f16x4*)(ap + 4);
                    frag[(ky + 1) & 1] =
                        __builtin_shufflevector(lo, hi, 0, 1, 2, 3, 4, 5, 6, 7);
                }
                const _Float16* bp = BtC + (size_t)(ky * R + run) * KSF + lane * 8;
                f16x8 b[NT];
                #pragma unroll
                for (int n = 0; n < NT; ++n)
                    b[n] = *(const f16x8*)(bp + n * 512);
                #pragma unroll
                for (int n = 0; n < NT; ++n) {
                    acc[0][n] = __builtin_amdgcn_mfma_f32_32x32x16_f16(
                        frag[ky & 1], b[n], acc[0][n], 0, 0, 0);
                    acc[1][n] = __builtin_amdgcn_mfma_f32_32x32x16_f16(
                        frag[(ky + 1) & 1], b[n], acc[1][n], 0, 0, 0);
                }
            }
        }
        __syncthreads();
    }

    // ---- epilogue: bias (+ReLU), store chunked fp16 [oc/20][y][x*20+oc%20] ----
    _Float16* outI = out + (size_t)img * outStride;
    #pragma unroll
    for (int nt = 0; nt < NT; ++nt) {
        int oc = nt * 32 + mcol;
        if (oc < OC) {
            float bv = bias[oc];
            int icc = oc / 20;
            int occ = oc - icc * 20;
            _Float16* base = outI + (size_t)icc * Ho * (Wo * 20) + occ;
            #pragma unroll
            for (int mt = 0; mt < 2; ++mt) {
                int y = y0 + wm * 2 + mt;
                _Float16* rowp = base + (size_t)y * (Wo * 20);
                #pragma unroll
                for (int reg = 0; reg < 16; ++reg) {
                    int x = x0 + (reg & 3) + 8 * (reg >> 2) + 4 * kh;
                    float v = acc[mt][nt][reg] + bv;
                    if (RELU) v = fmaxf(v, 0.0f);
                    rowp[(size_t)x * 20] = (_Float16)v;
                }
            }
        }
    }
}

// ---------------------------------------------------------------------------
// 1x1 conv: chunked-20 fp16 in -> NCHW fp32 out. No ReLU.
// ---------------------------------------------------------------------------
template<int NOUT>
__global__ __launch_bounds__(256) void conv1x1_kernel(
    const _Float16* __restrict__ in, const float* __restrict__ w,
    const float* __restrict__ bias, float* __restrict__ out,
    int N, int IC, long inStride, long outStride)
{
    int px = blockIdx.x * 256 + threadIdx.x;
    int img = blockIdx.y;
    if (px >= N) return;
    const _Float16* p = in + (size_t)img * inStride;
    float a[NOUT];
    #pragma unroll
    for (int o = 0; o < NOUT; ++o) a[o] = 0.0f;
    for (int ic = 0; ic < IC; ++ic) {
        int icc = ic / 20;
        int icl = ic - icc * 20;
        float v = (float)p[((size_t)icc * N + px) * 20 + icl];
        #pragma unroll
        for (int o = 0; o < NOUT; ++o) a[o] = fmaf(v, w[o * IC + ic], a[o]);
    }
    #pragma unroll
    for (int o = 0; o < NOUT; ++o)
        out[(size_t)img * outStride + (size_t)o * N + px] = a[o] + bias[o];
}

// ---------------------------------------------------------------------------
// Bicubic warp: disp fp32 + cf fp32 (NCHW) -> chunked-20 fp16 (ch 15..19 = 0).
// Arithmetic replicates reference (verified R1-R3).
// ---------------------------------------------------------------------------
__device__ __forceinline__ void cubicw(float t, float w[4])
{
    const float A = -0.75f;
    float u;
    u = t + 1.0f; w[0] = ((A * u - 5.0f * A) * u + 8.0f * A) * u - 4.0f * A;
    u = t;        w[1] = ((A + 2.0f) * u - (A + 3.0f)) * u * u + 1.0f;
    u = 1.0f - t; w[2] = ((A + 2.0f) * u - (A + 3.0f)) * u * u + 1.0f;
    u = 2.0f - t; w[3] = ((A * u - 5.0f * A) * u + 8.0f * A) * u - 4.0f * A;
}

__global__ __launch_bounds__(256) void warp_kernel(
    const float* __restrict__ disp, const float* __restrict__ cf,
    _Float16* __restrict__ outw)
{
    const int P = 65536;
    int idx = blockIdx.x * 256 + threadIdx.x;
    int img = blockIdx.y;
    const float* dI  = disp + (size_t)img * P;
    const float* cfI = cf + (size_t)img * 22 * P;
    _Float16* oI = outw + (size_t)img * 1310720 + (size_t)idx * 20;

    int u = idx >> 8;
    int v = idx & 255;

    float d  = dI[idx];
    float q0 = cfI[20 * P + idx];
    float q1 = cfI[21 * P + idx];

    for (int i = 0; i < 4; ++i) {
        const float* img5 = cfI + (size_t)(5 * i) * P;
        float p0 = img5[3 * P + idx];
        float p1 = img5[4 * P + idx];
        float lr = (float)u + (p0 - q0) * d;
        float lc = (float)v + (p1 - q1) * d;
        float gr = (lr / 255.0f - 0.5f) * 2.0f;
        float gc = (lc / 255.0f - 0.5f) * 2.0f;
        float x = ((gc + 1.0f) * 256.0f - 1.0f) * 0.5f;
        float y = ((gr + 1.0f) * 256.0f - 1.0f) * 0.5f;
        float xf = floorf(x), yf = floorf(y);
        float tx = x - xf, tyy = y - yf;
        float wx[4], wy[4];
        cubicw(tx, wx);
        cubicw(tyy, wy);
        int xi = (int)xf, yi = (int)yf;
        float a0 = 0.f, a1 = 0.f, a2 = 0.f;
        #pragma unroll
        for (int ii = 0; ii < 4; ++ii) {
            int yy = yi - 1 + ii;
            bool vy = (yy >= 0) && (yy < 256);
            int yc = min(max(yy, 0), 255);
            #pragma unroll
            for (int jj = 0; jj < 4; ++jj) {
                int xx = xi - 1 + jj;
                bool vv = vy && (xx >= 0) && (xx < 256);
                int xc = min(max(xx, 0), 255);
                float w = vv ? wy[ii] * wx[jj] : 0.0f;
                int pos = yc * 256 + xc;
                a0 = fmaf(img5[pos], w, a0);
                a1 = fmaf(img5[P + pos], w, a1);
                a2 = fmaf(img5[2 * P + pos], w, a2);
            }
        }
        oI[3 * i + 0] = (_Float16)a0;
        oI[3 * i + 1] = (_Float16)a1;
        oI[3 * i + 2] = (_Float16)a2;
    }
    oI[12] = (_Float16)d;
    oI[13] = (_Float16)q0;
    oI[14] = (_Float16)q1;
    #pragma unroll
    for (int c = 15; c < 20; ++c) oI[c] = (_Float16)0.0f;
}

// ---------------------------------------------------------------------------

extern "C" void kernel_launch(void* const* d_in, const int* in_sizes, int n_in,
                              void* d_out, int out_size, void* d_ws, size_t ws_size,
                              hipStream_t stream)
{
    const float* dF  = (const float*)d_in[0];
    const float* cF  = (const float*)d_in[1];
    const float* dw1 = (const float*)d_in[2];
    const float* db1 = (const float*)d_in[3];
    const float* dw2 = (const float*)d_in[4];
    const float* db2 = (const float*)d_in[5];
    const float* dw3 = (const float*)d_in[6];
    const float* db3 = (const float*)d_in[7];
    const float* dw4 = (const float*)d_in[8];
    const float* db4 = (const float*)d_in[9];
    const float* cw1 = (const float*)d_in[10];
    const float* cb1 = (const float*)d_in[11];
    const float* cw2 = (const float*)d_in[12];
    const float* cb2 = (const float*)d_in[13];
    const float* cw3 = (const float*)d_in[14];
    const float* cb3 = (const float*)d_in[15];
    const float* cw4 = (const float*)d_in[16];
    const float* cb4 = (const float*)d_in[17];

    float* outp = (float*)d_out;
    char* ws = (char*)d_ws;

    // ---- transformed-weight region (fp16, frag-native) ----
    // ksteps: d1 10*7*9=630 (G4), d2 5*5*7=175 (G4), d3 5*3*4=60 (G2),
    //         c1 1*7*9=63 (G4), c2=d2, c3=d3. bytes = ksteps*G*1024.
    const size_t O_D1 = 0;                        // 2,580,480
    const size_t O_D2 = O_D1 + 2580480;           //   716,800
    const size_t O_D3 = O_D2 + 716800;            //   122,880
    const size_t O_C1 = O_D3 + 122880;            //   258,048
    const size_t O_C2 = O_C1 + 258048;            //   716,800
    const size_t O_C3 = O_C2 + 716800;            //   122,880
    const size_t O_WEND = O_C3 + 122880;          // 4,517,888

    _Float16* bt_d1 = (_Float16*)(ws + O_D1);
    _Float16* bt_d2 = (_Float16*)(ws + O_D2);
    _Float16* bt_d3 = (_Float16*)(ws + O_D3);
    _Float16* bt_c1 = (_Float16*)(ws + O_C1);
    _Float16* bt_c2 = (_Float16*)(ws + O_C2);
    _Float16* bt_c3 = (_Float16*)(ws + O_C3);

    auto T = [&](const float* w, _Float16* bt, int IC, int OC, int G,
                 int K, int R, int ksteps) {
        int n = ksteps * G * 64;
        wtrans_kernel<<<(n + 255) / 256, 256, 0, stream>>>(w, bt, IC, OC, G, K, R, ksteps);
    };
    T(dw1, bt_d1, 200, 100, 4, 7, 9, 630);
    T(dw2, bt_d2, 100, 100, 4, 5, 7, 175);
    T(dw3, bt_d3, 100,  50, 2, 3, 4,  60);
    T(cw1, bt_c1,  15, 100, 4, 7, 9,  63);
    T(cw2, bt_c2, 100, 100, 4, 5, 7, 175);
    T(cw3, bt_c3, 100,  50, 2, 3, 4,  60);

    // ---- activation sizes (f16 elements per image) ----
    // dFc 10*268*268*20 = 14,364,800 ; bufA 5*262*262*20 = 6,864,400 ;
    // bufB 5*258*258*20 = 6,656,400 ; alias in dFc: bufC 3*256*256*20 =
    // 3,932,160 ; disp 65,536 f32 ; wrp 1,310,720.
    const size_t PER_IMG = (14364800ull + 6864400ull + 6656400ull) * 2; // bytes
    int batch = (ws_size >= O_WEND + 4ull * PER_IMG + 1024) ? 4
              : (ws_size >= O_WEND + 2ull * PER_IMG + 1024) ? 2 : 1;

    for (int g0 = 0; g0 < 4; g0 += batch) {
        const int N = batch;
        char* base = ws + O_WEND;
        _Float16* dFc  = (_Float16*)base;
        _Float16* bufA = (_Float16*)(base + 28729600ull * N);
        _Float16* bufB = (_Float16*)(base + (28729600ull + 13728800ull) * N);
        _Float16* bufC = (_Float16*)base;                          // alias dFc
        float*    disp = (float*)(base + 7864320ull * N);          // alias dFc
        _Float16* wrp  = (_Float16*)(base + (7864320ull + 262144ull) * N);

        const float* dFg = dF + (size_t)g0 * 200 * 268 * 268;
        const float* cFg = cF + (size_t)g0 * 22 * 65536;
        float* outg = outp + (size_t)g0 * 3 * 59536;

        convin_kernel<<<dim3(268, 10, N), 256, 0, stream>>>(dFg, dFc, 200);

        // disparity net  (tilesPerImg = xb * yb)
        conv_mfma<7, 4, true><<<297 * N, 256, 0, stream>>>(
            dFc, bt_d1, db1, bufA, 268, 268, 100, 262, 262, 10, 9, 297,
            14364800L, 6864400L);
        conv_mfma<5, 4, true><<<297 * N, 256, 0, stream>>>(
            bufA, bt_d2, db2, bufB, 262, 262, 100, 258, 258, 5, 9, 297,
            6864400L, 6656400L);
        conv_mfma<3, 2, true><<<256 * N, 256, 0, stream>>>(
            bufB, bt_d3, db3, bufC, 258, 258, 50, 256, 256, 5, 8, 256,
            6656400L, 3932160L);
        conv1x1_kernel<1><<<dim3(256, N), 256, 0, stream>>>(
            bufC, dw4, db4, disp, 65536, 50, 3932160L, 65536L);

        // warp
        warp_kernel<<<dim3(256, N), 256, 0, stream>>>(disp, cFg, wrp);

        // color net
        conv_mfma<7, 4, true><<<256 * N, 256, 0, stream>>>(
            wrp, bt_c1, cb1, bufA, 256, 256, 100, 250, 250, 1, 8, 256,
            1310720L, 6250000L);
        conv_mfma<5, 4, true><<<248 * N, 256, 0, stream>>>(
            bufA, bt_c2, cb2, bufB, 250, 250, 100, 246, 246, 5, 8, 248,
            6250000L, 6051600L);
        conv_mfma<3, 2, true><<<248 * N, 256, 0, stream>>>(
            bufB, bt_c3, cb3, bufC, 246, 246, 50, 244, 244, 5, 8, 248,
            6051600L, 3932160L);
        conv1x1_kernel<3><<<dim3(233, N), 256, 0, stream>>>(
            bufC, cw4, cb4, outg, 59536, 50, 3932160L, 178608L);
    }
}

// Round 5
// 1752.868 us; speedup vs baseline: 1.2530x; 1.2530x over previous
//
#include <hip/hip_runtime.h>
#include <cstddef>
#include <cstdint>

typedef _Float16 f16x8 __attribute__((ext_vector_type(8)));
typedef _Float16 f16x4 __attribute__((ext_vector_type(4)));
typedef float    f32x16 __attribute__((ext_vector_type(16)));

// ---------------------------------------------------------------------------
// Weight transform: OIHW fp32 -> Bt[kstep][g][lane][8j] fp16 (frag-native for
// mfma_f32_32x32x16_f16 B operand: n = lane&31, k = (lane>>5)*8 + j).
// kstep = (chunk*K + ky)*R + run; flat = run*16 + k; x_off = flat/20,
// ic = chunk*20 + flat%20. Zero for oc>=OC, ic>=IC, x_off>=K.
// ---------------------------------------------------------------------------
__global__ __launch_bounds__(256) void wtrans_kernel(
    const float* __restrict__ w, _Float16* __restrict__ Bt,
    int IC, int OC, int G, int K, int R, int ksteps)
{
    int gid = blockIdx.x * 256 + threadIdx.x;
    if (gid >= ksteps * G * 64) return;
    int ks   = gid / (G * 64);
    int rr   = gid - ks * G * 64;
    int g    = rr >> 6;
    int lane = rr & 63;
    int run = ks % R;
    int t2  = ks / R;
    int ky  = t2 % K;
    int chunk = t2 / K;
    int oc = g * 32 + (lane & 31);
    int kh = lane >> 5;
    _Float16 tmp[8];
    #pragma unroll
    for (int j = 0; j < 8; ++j) {
        int flat = run * 16 + kh * 8 + j;
        int xo  = flat / 20;
        int icl = flat - xo * 20;
        int ic  = chunk * 20 + icl;
        float v = 0.0f;
        if (oc < OC && ic < IC && xo < K)
            v = w[(((size_t)oc * IC + ic) * K + ky) * K + xo];
        tmp[j] = (_Float16)v;
    }
    *(uint4*)(Bt + (size_t)gid * 8) = *(uint4*)tmp;
}

// ---------------------------------------------------------------------------
// Input pre-convert: NCHW fp32 (200ch) -> chunked fp16 [img][10][268][268*20].
// ---------------------------------------------------------------------------
__global__ __launch_bounds__(256) void convin_kernel(
    const float* __restrict__ src, _Float16* __restrict__ dst, int IC)
{
    constexpr int W = 268;
    constexpr int PADS = 272;
    __shared__ float s[20 * PADS];
    int y = blockIdx.x, chunk = blockIdx.y, img = blockIdx.z;
    int tid = threadIdx.x;
    for (int e = tid; e < 20 * W; e += 256) {
        int icl = e / W;
        int x = e - icl * W;
        int ic = chunk * 20 + icl;
        float v = 0.0f;
        if (ic < IC)
            v = src[(((size_t)img * IC + ic) * W + y) * W + x];
        s[icl * PADS + x] = v;
    }
    __syncthreads();
    _Float16* outRow = dst + ((size_t)(img * 10 + chunk) * W + y) * (W * 20);
    for (int u = tid; u < W * 20 / 8; u += 256) {
        _Float16 t[8];
        #pragma unroll
        for (int q = 0; q < 8; ++q) {
            int e = u * 8 + q;
            int px = e / 20;
            int c  = e - px * 20;
            t[q] = (_Float16)s[c * PADS + px];
        }
        *(uint4*)(outRow + (size_t)u * 8) = *(uint4*)t;
    }
}

// ---------------------------------------------------------------------------
// Implicit-GEMM conv, MFMA 32x32x16 fp16.
// R5 = R0 (best: 775us d1, MfmaUtil 46) with ONE change: the compute loops
// are run-outer / ky-inner with a 4-fragment rolling A window.
// Evidence (R0/R3/R4): MfmaUtil pinned at ~44-46% == A-LDS BW cap
// (4 frag-reads per 8 MFMAs = 512 B/MFMA -> 254 B/cyc demand vs ~112
// ceiling); raising occupancy (R3) didn't move it; trading LDS for global-B
// (R4) regressed (B must stay at 256 B/MFMA).
// Window: at fixed run, output rows wm*4+mt need input rows wm*4+ky+mt;
// consecutive ky reuse 3 of 4 fragments -> A-reads per run-column K+3 vs 4K
// (2.8x less LDS traffic, ~97 B/cyc < ceiling), B traffic/addresses
// unchanged. Incoming fragment feeds only the mt=3 MFMA (ordered last).
// Window indices static after full ky-unroll (no scratch). Everything else
// (stage, barriers, epilogue, occupancy bounds, launch) identical to R0.
// Block: BM = WM*4 y-rows x 32 px x 64 oc (2 groups); 4 waves:
//   WN==2: wm=wave&1, wn=wave>>1 (oc-half of 128); WN==1: wm=wave, wn=0.
// m-tile = 1 y-row x 32 x; A lane: m=lane&31 (x), k=(lane>>5)*8+j.
// C/D: col(n)=lane&31, row(x)=(reg&3)+8*(reg>>2)+4*(lane>>5).
// ---------------------------------------------------------------------------
template<int K, int WM, int WN, bool RELU>
__global__ __launch_bounds__(256, 2) void conv_mfma(
    const _Float16* __restrict__ in, const _Float16* __restrict__ Bt,
    const float* __restrict__ bias, _Float16* __restrict__ out,
    int Hin, int Win, int OC, int Ho, int Wo,
    int nchunks, int xb, int tilesPerImg,
    long inStride, long outStride)
{
    constexpr int CB = 20;
    constexpr int R  = (K * CB + 15) / 16;
    constexpr int BM = WM * 4;
    constexpr int PH = BM + K - 1;
    constexpr int MAXF = 31 * CB + R * 16;
    constexpr int PW = (((MAXF + CB - 1) / CB) + 1) & ~1;
    constexpr int ROWF = PW * CB;          // f16 per LDS row
    constexpr int UROW = ROWF / 8;         // 16B units per row
    constexpr int TOT  = PH * UROW;        // 16B units per buffer
    constexpr int G    = WN * 2;           // oc32-groups per kstep
    constexpr int KSF  = G * 512;          // f16 per kstep in Bt

    __shared__ __align__(16) _Float16 s[PH * ROWF];

    const int tid  = threadIdx.x;
    const int lane = tid & 63;
    const int wave = tid >> 6;
    const int wm   = (WN == 2) ? (wave & 1) : wave;
    const int wn   = (WN == 2) ? (wave >> 1) : 0;
    const int mcol = lane & 31;
    const int kh   = lane >> 5;
    const int alane = mcol * CB + kh * 8;

    int t = blockIdx.x;
    int img = t / tilesPerImg;
    int rem = t - img * tilesPerImg;
    int byi = rem / xb;
    int bxi = rem - byi * xb;
    int y0 = byi * BM; if (y0 > Ho - BM) y0 = Ho - BM;
    int x0 = bxi * 32; if (x0 > Wo - 32) x0 = Wo - 32;

    const _Float16* inI = in + (size_t)img * inStride;

    f32x16 acc[4][2];
    #pragma unroll
    for (int m = 0; m < 4; ++m)
        #pragma unroll
        for (int n = 0; n < 2; ++n)
            acc[m][n] = (f32x16)(0.0f);

    const int rowE = Win * CB;
    const int mxo  = rowE - 8;
    const size_t chStride = (size_t)Hin * rowE;

    #pragma unroll 1
    for (int chunk = 0; chunk < nchunks; ++chunk) {
        // ---- stage A patch (contiguous 16B units per row, clamped) ----
        const _Float16* inC = inI + chunk * chStride + (size_t)y0 * rowE;
        #pragma unroll 1
        for (int e = tid; e < TOT; e += 256) {
            int py = e / UROW;
            int uu = e - py * UROW;
            int off = x0 * CB + uu * 8;
            if (off > mxo) off = mxo;     // clamped slots only feed zero-B taps
            uint4 val = *(const uint4*)(inC + (size_t)py * rowE + off);
            *(uint4*)&s[(size_t)e * 8] = val;
        }
        __syncthreads();

        const _Float16* BtC = Bt + (size_t)(chunk * K) * R * KSF;
        #pragma unroll 1
        for (int run = 0; run < R; ++run) {
            const int abase = (wm * 4) * ROWF + alane + run * 16;
            const _Float16* BtR = BtC + (size_t)run * KSF + (wn * 128 + lane) * 8;
            // rolling 4-fragment window over relative rows ky..ky+3
            f16x8 w[4];
            #pragma unroll
            for (int p = 0; p < 3; ++p) {
                const _Float16* ap = &s[abase + p * ROWF];
                f16x4 lo = *(const f16x4*)ap;
                f16x4 hi = *(const f16x4*)(ap + 4);
                w[p] = __builtin_shufflevector(lo, hi, 0, 1, 2, 3, 4, 5, 6, 7);
            }
            #pragma unroll
            for (int ky = 0; ky < K; ++ky) {
                {   // incoming fragment: relative row ky+3 (feeds mt=3 only)
                    const _Float16* ap = &s[abase + (ky + 3) * ROWF];
                    f16x4 lo = *(const f16x4*)ap;
                    f16x4 hi = *(const f16x4*)(ap + 4);
                    w[(ky + 3) & 3] =
                        __builtin_shufflevector(lo, hi, 0, 1, 2, 3, 4, 5, 6, 7);
                }
                const _Float16* bp = BtR + (size_t)(ky * R) * KSF;
                f16x8 b0 = *(const f16x8*)bp;
                f16x8 b1 = *(const f16x8*)(bp + 512);
                #pragma unroll
                for (int mt = 0; mt < 4; ++mt) {
                    f16x8 a = w[(ky + mt) & 3];
                    acc[mt][0] = __builtin_amdgcn_mfma_f32_32x32x16_f16(a, b0, acc[mt][0], 0, 0, 0);
                    acc[mt][1] = __builtin_amdgcn_mfma_f32_32x32x16_f16(a, b1, acc[mt][1], 0, 0, 0);
                }
            }
        }
        __syncthreads();
    }

    // ---- epilogue: bias (+ReLU), store chunked fp16 [oc/20][y][x*20+oc%20] ----
    _Float16* outI = out + (size_t)img * outStride;
    #pragma unroll
    for (int nt = 0; nt < 2; ++nt) {
        int oc = (wn * 2 + nt) * 32 + mcol;
        if (oc < OC) {
            float bv = bias[oc];
            int icc = oc / 20;
            int occ = oc - icc * 20;
            _Float16* base = outI + (size_t)icc * Ho * (Wo * 20) + occ;
            #pragma unroll
            for (int mt = 0; mt < 4; ++mt) {
                int y = y0 + wm * 4 + mt;
                _Float16* rowp = base + (size_t)y * (Wo * 20);
                #pragma unroll
                for (int reg = 0; reg < 16; ++reg) {
                    int x = x0 + (reg & 3) + 8 * (reg >> 2) + 4 * kh;
                    float v = acc[mt][nt][reg] + bv;
                    if (RELU) v = fmaxf(v, 0.0f);
                    rowp[(size_t)x * 20] = (_Float16)v;
                }
            }
        }
    }
}

// ---------------------------------------------------------------------------
// 1x1 conv: chunked-20 fp16 in -> NCHW fp32 out. No ReLU.
// ---------------------------------------------------------------------------
template<int NOUT>
__global__ __launch_bounds__(256) void conv1x1_kernel(
    const _Float16* __restrict__ in, const float* __restrict__ w,
    const float* __restrict__ bias, float* __restrict__ out,
    int N, int IC, long inStride, long outStride)
{
    int px = blockIdx.x * 256 + threadIdx.x;
    int img = blockIdx.y;
    if (px >= N) return;
    const _Float16* p = in + (size_t)img * inStride;
    float a[NOUT];
    #pragma unroll
    for (int o = 0; o < NOUT; ++o) a[o] = 0.0f;
    for (int ic = 0; ic < IC; ++ic) {
        int icc = ic / 20;
        int icl = ic - icc * 20;
        float v = (float)p[((size_t)icc * N + px) * 20 + icl];
        #pragma unroll
        for (int o = 0; o < NOUT; ++o) a[o] = fmaf(v, w[o * IC + ic], a[o]);
    }
    #pragma unroll
    for (int o = 0; o < NOUT; ++o)
        out[(size_t)img * outStride + (size_t)o * N + px] = a[o] + bias[o];
}

// ---------------------------------------------------------------------------
// Bicubic warp: disp fp32 + cf fp32 (NCHW) -> chunked-20 fp16 (ch 15..19 = 0).
// Arithmetic replicates reference (verified R1-R3).
// ---------------------------------------------------------------------------
__device__ __forceinline__ void cubicw(float t, float w[4])
{
    const float A = -0.75f;
    float u;
    u = t + 1.0f; w[0] = ((A * u - 5.0f * A) * u + 8.0f * A) * u - 4.0f * A;
    u = t;        w[1] = ((A + 2.0f) * u - (A + 3.0f)) * u * u + 1.0f;
    u = 1.0f - t; w[2] = ((A + 2.0f) * u - (A + 3.0f)) * u * u + 1.0f;
    u = 2.0f - t; w[3] = ((A * u - 5.0f * A) * u + 8.0f * A) * u - 4.0f * A;
}

__global__ __launch_bounds__(256) void warp_kernel(
    const float* __restrict__ disp, const float* __restrict__ cf,
    _Float16* __restrict__ outw)
{
    const int P = 65536;
    int idx = blockIdx.x * 256 + threadIdx.x;
    int img = blockIdx.y;
    const float* dI  = disp + (size_t)img * P;
    const float* cfI = cf + (size_t)img * 22 * P;
    _Float16* oI = outw + (size_t)img * 1310720 + (size_t)idx * 20;

    int u = idx >> 8;
    int v = idx & 255;

    float d  = dI[idx];
    float q0 = cfI[20 * P + idx];
    float q1 = cfI[21 * P + idx];

    for (int i = 0; i < 4; ++i) {
        const float* img5 = cfI + (size_t)(5 * i) * P;
        float p0 = img5[3 * P + idx];
        float p1 = img5[4 * P + idx];
        float lr = (float)u + (p0 - q0) * d;
        float lc = (float)v + (p1 - q1) * d;
        float gr = (lr / 255.0f - 0.5f) * 2.0f;
        float gc = (lc / 255.0f - 0.5f) * 2.0f;
        float x = ((gc + 1.0f) * 256.0f - 1.0f) * 0.5f;
        float y = ((gr + 1.0f) * 256.0f - 1.0f) * 0.5f;
        float xf = floorf(x), yf = floorf(y);
        float tx = x - xf, tyy = y - yf;
        float wx[4], wy[4];
        cubicw(tx, wx);
        cubicw(tyy, wy);
        int xi = (int)xf, yi = (int)yf;
        float a0 = 0.f, a1 = 0.f, a2 = 0.f;
        #pragma unroll
        for (int ii = 0; ii < 4; ++ii) {
            int yy = yi - 1 + ii;
            bool vy = (yy >= 0) && (yy < 256);
            int yc = min(max(yy, 0), 255);
            #pragma unroll
            for (int jj = 0; jj < 4; ++jj) {
                int xx = xi - 1 + jj;
                bool vv = vy && (xx >= 0) && (xx < 256);
                int xc = min(max(xx, 0), 255);
                float w = vv ? wy[ii] * wx[jj] : 0.0f;
                int pos = yc * 256 + xc;
                a0 = fmaf(img5[pos], w, a0);
                a1 = fmaf(img5[P + pos], w, a1);
                a2 = fmaf(img5[2 * P + pos], w, a2);
            }
        }
        oI[3 * i + 0] = (_Float16)a0;
        oI[3 * i + 1] = (_Float16)a1;
        oI[3 * i + 2] = (_Float16)a2;
    }
    oI[12] = (_Float16)d;
    oI[13] = (_Float16)q0;
    oI[14] = (_Float16)q1;
    #pragma unroll
    for (int c = 15; c < 20; ++c) oI[c] = (_Float16)0.0f;
}

// ---------------------------------------------------------------------------

extern "C" void kernel_launch(void* const* d_in, const int* in_sizes, int n_in,
                              void* d_out, int out_size, void* d_ws, size_t ws_size,
                              hipStream_t stream)
{
    const float* dF  = (const float*)d_in[0];
    const float* cF  = (const float*)d_in[1];
    const float* dw1 = (const float*)d_in[2];
    const float* db1 = (const float*)d_in[3];
    const float* dw2 = (const float*)d_in[4];
    const float* db2 = (const float*)d_in[5];
    const float* dw3 = (const float*)d_in[6];
    const float* db3 = (const float*)d_in[7];
    const float* dw4 = (const float*)d_in[8];
    const float* db4 = (const float*)d_in[9];
    const float* cw1 = (const float*)d_in[10];
    const float* cb1 = (const float*)d_in[11];
    const float* cw2 = (const float*)d_in[12];
    const float* cb2 = (const float*)d_in[13];
    const float* cw3 = (const float*)d_in[14];
    const float* cb3 = (const float*)d_in[15];
    const float* cw4 = (const float*)d_in[16];
    const float* cb4 = (const float*)d_in[17];

    float* outp = (float*)d_out;
    char* ws = (char*)d_ws;

    // ---- transformed-weight region (fp16, frag-native) ----
    // ksteps: d1 10*7*9=630 (G4), d2 5*5*7=175 (G4), d3 5*3*4=60 (G2),
    //         c1 1*7*9=63 (G4), c2=d2, c3=d3. bytes = ksteps*G*1024.
    const size_t O_D1 = 0;                        // 2,580,480
    const size_t O_D2 = O_D1 + 2580480;           //   716,800
    const size_t O_D3 = O_D2 + 716800;            //   122,880
    const size_t O_C1 = O_D3 + 122880;            //   258,048
    const size_t O_C2 = O_C1 + 258048;            //   716,800
    const size_t O_C3 = O_C2 + 716800;            //   122,880
    const size_t O_WEND = O_C3 + 122880;          // 4,517,888

    _Float16* bt_d1 = (_Float16*)(ws + O_D1);
    _Float16* bt_d2 = (_Float16*)(ws + O_D2);
    _Float16* bt_d3 = (_Float16*)(ws + O_D3);
    _Float16* bt_c1 = (_Float16*)(ws + O_C1);
    _Float16* bt_c2 = (_Float16*)(ws + O_C2);
    _Float16* bt_c3 = (_Float16*)(ws + O_C3);

    auto T = [&](const float* w, _Float16* bt, int IC, int OC, int G,
                 int K, int R, int ksteps) {
        int n = ksteps * G * 64;
        wtrans_kernel<<<(n + 255) / 256, 256, 0, stream>>>(w, bt, IC, OC, G, K, R, ksteps);
    };
    T(dw1, bt_d1, 200, 100, 4, 7, 9, 630);
    T(dw2, bt_d2, 100, 100, 4, 5, 7, 175);
    T(dw3, bt_d3, 100,  50, 2, 3, 4,  60);
    T(cw1, bt_c1,  15, 100, 4, 7, 9,  63);
    T(cw2, bt_c2, 100, 100, 4, 5, 7, 175);
    T(cw3, bt_c3, 100,  50, 2, 3, 4,  60);

    // ---- activation sizes (f16 elements per image) ----
    // dFc 10*268*268*20 = 14,364,800 ; bufA 5*262*262*20 = 6,864,400 ;
    // bufB 5*258*258*20 = 6,656,400 ; alias in dFc: bufC 3*256*256*20 =
    // 3,932,160 ; disp 65,536 f32 ; wrp 1,310,720.
    const size_t PER_IMG = (14364800ull + 6864400ull + 6656400ull) * 2; // bytes
    int batch = (ws_size >= O_WEND + 4ull * PER_IMG + 1024) ? 4
              : (ws_size >= O_WEND + 2ull * PER_IMG + 1024) ? 2 : 1;

    for (int g0 = 0; g0 < 4; g0 += batch) {
        const int N = batch;
        char* base = ws + O_WEND;
        _Float16* dFc  = (_Float16*)base;
        _Float16* bufA = (_Float16*)(base + 28729600ull * N);
        _Float16* bufB = (_Float16*)(base + (28729600ull + 13728800ull) * N);
        _Float16* bufC = (_Float16*)base;                          // alias dFc
        float*    disp = (float*)(base + 7864320ull * N);          // alias dFc
        _Float16* wrp  = (_Float16*)(base + (7864320ull + 262144ull) * N);

        const float* dFg = dF + (size_t)g0 * 200 * 268 * 268;
        const float* cFg = cF + (size_t)g0 * 22 * 65536;
        float* outg = outp + (size_t)g0 * 3 * 59536;

        convin_kernel<<<dim3(268, 10, N), 256, 0, stream>>>(dFg, dFc, 200);

        // disparity net
        conv_mfma<7, 2, 2, true><<<9 * 33 * N, 256, 0, stream>>>(
            dFc, bt_d1, db1, bufA, 268, 268, 100, 262, 262, 10, 9, 9 * 33,
            14364800L, 6864400L);
        conv_mfma<5, 2, 2, true><<<9 * 33 * N, 256, 0, stream>>>(
            bufA, bt_d2, db2, bufB, 262, 262, 100, 258, 258, 5, 9, 9 * 33,
            6864400L, 6656400L);
        conv_mfma<3, 4, 1, true><<<8 * 16 * N, 256, 0, stream>>>(
            bufB, bt_d3, db3, bufC, 258, 258, 50, 256, 256, 5, 8, 8 * 16,
            6656400L, 3932160L);
        conv1x1_kernel<1><<<dim3(256, N), 256, 0, stream>>>(
            bufC, dw4, db4, disp, 65536, 50, 3932160L, 65536L);

        // warp
        warp_kernel<<<dim3(256, N), 256, 0, stream>>>(disp, cFg, wrp);

        // color net
        conv_mfma<7, 2, 2, true><<<8 * 32 * N, 256, 0, stream>>>(
            wrp, bt_c1, cb1, bufA, 256, 256, 100, 250, 250, 1, 8, 8 * 32,
            1310720L, 6250000L);
        conv_mfma<5, 2, 2, true><<<8 * 31 * N, 256, 0, stream>>>(
            bufA, bt_c2, cb2, bufB, 250, 250, 100, 246, 246, 5, 8, 8 * 31,
            6250000L, 6051600L);
        conv_mfma<3, 4, 1, true><<<8 * 16 * N, 256, 0, stream>>>(
            bufB, bt_c3, cb3, bufC, 246, 246, 50, 244, 244, 5, 8, 8 * 16,
            6051600L, 3932160L);
        conv1x1_kernel<3><<<dim3(233, N), 256, 0, stream>>>(
            bufC, cw4, cb4, outg, 59536, 50, 3932160L, 178608L);
    }
}